// Round 9
// baseline (291.020 us; speedup 1.0000x reference)
//
#include <hip/hip_runtime.h>
#include <stdint.h>
#include <stddef.h>

// ---------------- problem constants ----------------
#define SEQ   2048
#define BATCH 2
#define HID   2048
#define NH    16
#define HD    128
#define MTOT  (SEQ*BATCH)   // 4096
#define NQKV  (3*HID)       // 6144
#define KDIM  HID           // 2048
#define LOG2E 1.4426950408889634f

#define BK64    64
#define NT64    (KDIM/BK64)   // 32

typedef short  bf16x8 __attribute__((ext_vector_type(8)));  // 8 bf16 in 4 VGPRs
typedef float  f32x4  __attribute__((ext_vector_type(4)));

__device__ __forceinline__ unsigned short f2bf(float f) {
  union { float f; uint32_t u; } a; a.f = f;
  uint32_t r = a.u + 0x7fffu + ((a.u >> 16) & 1u);   // RNE
  return (unsigned short)(r >> 16);
}

__device__ __forceinline__ f32x4 mfma16(bf16x8 a, bf16x8 b, f32x4 c) {
  return __builtin_amdgcn_mfma_f32_16x16x32_bf16(a, b, c, 0, 0, 0);
}

// async global->LDS, 16B per lane; LDS dest = wave-uniform base + lane*16
__device__ __forceinline__ void gl_lds16(const unsigned short* g, unsigned short* l) {
  __builtin_amdgcn_global_load_lds(
      (const __attribute__((address_space(1))) void*)g,
      (__attribute__((address_space(3))) void*)l, 16, 0, 0);
}

// ---------------- fused fp32 -> bf16 convert (3 tensors, 1 launch) ----------------
__global__ void cvt3_f32_bf16(const float* __restrict__ a, unsigned short* __restrict__ oa, int na,
                              const float* __restrict__ b, unsigned short* __restrict__ ob, int nb,
                              const float* __restrict__ c, unsigned short* __restrict__ oc, int nc) {
  int i = blockIdx.x * blockDim.x + threadIdx.x;
  int stride = gridDim.x * blockDim.x;
  int ntot = na + nb + nc;
  for (; i < ntot; i += stride) {
    const float* src; unsigned short* dst; int j;
    if (i < na)           { src = a; dst = oa; j = i; }
    else if (i < na + nb) { src = b; dst = ob; j = i - na; }
    else                  { src = c; dst = oc; j = i - na - nb; }
    float4 f = reinterpret_cast<const float4*>(src)[j];
    ushort4 o;
    o.x = f2bf(f.x); o.y = f2bf(f.y); o.z = f2bf(f.z); o.w = f2bf(f.w);
    reinterpret_cast<ushort4*>(dst)[j] = o;
  }
}

// =====================================================================
// m201-template 256x256 GEMM (qkv): BK=64, 512 thr = 8 waves (2M x 4N),
// per-wave output 128x64 (acc[8][4] = 128 VGPR).
// LDS: 2 buffers x 64KB (A [256][64] @0, B [256][64] @16384 shorts),
// involution granule swizzle LDS[r][g] = glob[r][g ^ (r&7)].
// 4 phases per K-tile; phase = C-quadrant (mh, ks), exactly 16 MFMA:
//   P0 (mh0,ks0): reads B(ks0)4 + A(mh0,ks0)4 = 8   stage B[0],B[64]
//   P1 (mh1,ks0): reads A(mh1,ks0)4                 stage B[128],B[192]
//   P2 (mh0,ks1): reads B(ks1)4 + A(mh0,ks1)4 = 8   stage A[0],A[128]
//   P3 (mh1,ks1): reads A(mh1,ks1)4                 stage A[64],A[192]
// Stages (8 rounds/tile, 2/phase) go into the OTHER buffer (race-free).
// vmcnt(2) at P0 and P3 only (never 0 in steady state):
//   P3: in-flight 8 -> retires first 6 (B-all + A[0],A[128]) needed at
//       next P0; leaves A[64],A[192] flying (needed at next P1).
//   P0: in-flight 4 -> retires prev-P3's 2 before P1 reads them.
// Phase: reads/stage -> [vmcnt] -> bar -> lgkm(0)+schedbar -> setprio(1)
//        16 MFMA setprio(0) -> bar.
// Grid 16 x 24 = 384 blocks (1.5 dispatch waves; 62% util >> tail cost).
// =====================================================================

#define QBUF2 32768   // shorts per LDS buffer: A 16384 + B 16384

#define QSTA(R) gl_lds16(Asrc + (size_t)(R) * KDIM + koff, &db[((R) + w * 8) * 64])
#define QSTB(R) gl_lds16(Bsrc + (size_t)(R) * KDIM + koff, &db[16384 + ((R) + w * 8) * 64])

#define RD_A4q(MH, GA, SB) do {                                               \
    aF[0] = *(const bf16x8*)&(SB)[abase + ((MH) * 4 + 0) * 1024 + (GA)];      \
    aF[1] = *(const bf16x8*)&(SB)[abase + ((MH) * 4 + 1) * 1024 + (GA)];      \
    aF[2] = *(const bf16x8*)&(SB)[abase + ((MH) * 4 + 2) * 1024 + (GA)];      \
    aF[3] = *(const bf16x8*)&(SB)[abase + ((MH) * 4 + 3) * 1024 + (GA)];      \
  } while (0)

#define RD_B4q(GA, SB) do {                                                   \
    bF[0] = *(const bf16x8*)&(SB)[bbase + 0 * 1024 + (GA)];                   \
    bF[1] = *(const bf16x8*)&(SB)[bbase + 1 * 1024 + (GA)];                   \
    bF[2] = *(const bf16x8*)&(SB)[bbase + 2 * 1024 + (GA)];                   \
    bF[3] = *(const bf16x8*)&(SB)[bbase + 3 * 1024 + (GA)];                   \
  } while (0)

#define QPH(MH, RDOP, STOP, VMOP) do {                                        \
    RDOP;                                                                     \
    STOP;                                                                     \
    VMOP;                                                                     \
    asm volatile("s_barrier" ::: "memory");                                   \
    asm volatile("s_waitcnt lgkmcnt(0)" ::: "memory");                        \
    __builtin_amdgcn_sched_barrier(0);                                        \
    __builtin_amdgcn_s_setprio(1);                                            \
    _Pragma("unroll")                                                         \
    for (int m_ = 0; m_ < 4; ++m_)                                            \
      _Pragma("unroll")                                                       \
      for (int n_ = 0; n_ < 4; ++n_)                                          \
        acc[(MH) * 4 + m_][n_] = mfma16(aF[m_], bF[n_], acc[(MH) * 4 + m_][n_]); \
    __builtin_amdgcn_sched_barrier(0);                                        \
    __builtin_amdgcn_s_setprio(0);                                            \
    asm volatile("s_barrier" ::: "memory");                                   \
  } while (0)

#define VMC2 asm volatile("s_waitcnt vmcnt(2)" ::: "memory")
#define VMC0 asm volatile("s_waitcnt vmcnt(0)" ::: "memory")

// grid: 384 blocks (16 m x 24 n), XCD-swizzled (384 % 8 == 0, q = 48).
__global__ __launch_bounds__(512, 1) void qkv_gemm(
    const unsigned short* __restrict__ A,
    const unsigned short* __restrict__ B,
    const float* __restrict__ bias,
    unsigned short* __restrict__ Qo,
    unsigned short* __restrict__ Ko,
    unsigned short* __restrict__ Vt)      // V written TRANSPOSED [bh][d][s]
{
  __shared__ unsigned short smb[2 * QBUF2];   // 128 KB
  const int id  = blockIdx.x;
  const int swz = (id & 7) * 48 + (id >> 3);
  const int m0 = (swz / 24) * 256, n0 = (swz % 24) * 256;
  const int t = threadIdx.x, l = t & 63, w = t >> 6;
  const int wm = w >> 2, wn = w & 3;
  const int fr = l & 15, fg = l >> 4;
  const int abase = (wm * 128 + fr) * 64;
  const int bbase = 16384 + (wn * 64 + fr) * 64;
  const int ga0 = ((fg    ) ^ (fr & 7)) * 8;   // ks0 granule
  const int ga1 = ((fg + 4) ^ (fr & 7)) * 8;   // ks1 granule
  const int srcrow = w * 8 + (l >> 3);
  const int sgr    = ((l & 7) ^ (l >> 3)) * 8;
  const unsigned short* Asrc = A + (size_t)(m0 + srcrow) * KDIM + sgr;
  const unsigned short* Bsrc = B + (size_t)(n0 + srcrow) * KDIM + sgr;

  f32x4 acc[8][4] = {};
  bf16x8 aF[4], bF[4];

  { // prologue: stage tile 0 (order B0,B64,B128,B192,A0,A128,A64,A192)
    unsigned short* db = smb;
    size_t koff = 0;
    QSTB(0); QSTB(64); QSTB(128); QSTB(192);
    QSTA(0); QSTA(128); QSTA(64); QSTA(192);
  }
  VMC2;                                     // A64,A192 still in flight
  asm volatile("s_barrier" ::: "memory");

#pragma unroll 1
  for (int kt = 0; kt < NT64 - 1; ++kt) {
    const unsigned short* sb = &smb[(kt & 1) * QBUF2];
    unsigned short* db = &smb[((kt + 1) & 1) * QBUF2];
    size_t koff = (size_t)(kt + 1) * BK64;
    QPH(0, RD_B4q(ga0, sb); RD_A4q(0, ga0, sb), QSTB(0);   QSTB(64),  VMC2);
    QPH(1, RD_A4q(1, ga0, sb),                  QSTB(128); QSTB(192), (void)0);
    QPH(0, RD_B4q(ga1, sb); RD_A4q(0, ga1, sb), QSTA(0);   QSTA(128), (void)0);
    QPH(1, RD_A4q(1, ga1, sb),                  QSTA(64);  QSTA(192), VMC2);
  }
  { // final tile: no staging; P0 drains the last 2 rounds
    const unsigned short* sb = &smb[((NT64 - 1) & 1) * QBUF2];
    QPH(0, RD_B4q(ga0, sb); RD_A4q(0, ga0, sb), (void)0, VMC0);
    QPH(1, RD_A4q(1, ga0, sb),                  (void)0, (void)0);
    QPH(0, RD_B4q(ga1, sb); RD_A4q(0, ga1, sb), (void)0, (void)0);
    QPH(1, RD_A4q(1, ga1, sb),                  (void)0, (void)0);
  }

  // epilogue: bias (+ q-scale fold); Q,K -> [b][h][s][d]; V -> [b][h][d][s]
#pragma unroll
  for (int n = 0; n < 4; ++n) {
    int ncol = n0 + wn * 64 + n * 16 + fr;
    float bv = bias[ncol];
    int head = ncol / 384;
    int rem  = ncol - head * 384;
    int wi   = rem >> 7;          // 0=q 1=k 2=v
    int d    = rem & 127;
#pragma unroll
    for (int m = 0; m < 8; ++m) {
#pragma unroll
      for (int j = 0; j < 4; ++j) {
        int r = m0 + wm * 128 + m * 16 + fg * 4 + j;
        int s = r >> 1, bb = r & 1;
        float val = acc[m][n][j] + bv;
        if (wi == 0) {
          val *= 0.08838834764831845f;   // fold 1/sqrt(128) into Q
          Qo[(((size_t)(bb * NH + head)) * SEQ + s) * HD + d] = f2bf(val);
        } else if (wi == 1) {
          Ko[(((size_t)(bb * NH + head)) * SEQ + s) * HD + d] = f2bf(val);
        } else {
          Vt[(((size_t)(bb * NH + head)) * HD + d) * SEQ + s] = f2bf(val);
        }
      }
    }
  }
}

// =====================================================================
// FREE-FLOW dense GEMM: BM=256, BN=128, BK=64, 512 thr = 8 waves
// (4M x 2N), per-wave 64x64 (acc[4][4]).  LDS 2 x 48KB.
// Grid 16x16 = 256 blocks = 1 full dispatch wave.
// =====================================================================

#define DBUFS 24576   // shorts per buffer: A 16384 + B 8192

#define DSTAGE6 do {                                                          \
    gl_lds16(Aw + koff,                    &db[(w * 4 + 0) * 512]);           \
    gl_lds16(Aw + koff + 8  * KDIM,        &db[(w * 4 + 1) * 512]);           \
    gl_lds16(Aw + koff + 16 * KDIM,        &db[(w * 4 + 2) * 512]);           \
    gl_lds16(Aw + koff + 24 * KDIM,        &db[(w * 4 + 3) * 512]);           \
    gl_lds16(Bw + koff,                    &db[16384 + (w * 2 + 0) * 512]);   \
    gl_lds16(Bw + koff + 8 * KDIM,         &db[16384 + (w * 2 + 1) * 512]);   \
  } while (0)

#define MFMA_D(X, Y, M) do {                                                  \
    _Pragma("unroll")                                                         \
    for (int n_ = 0; n_ < 4; ++n_) {                                          \
      acc[M][n_] = mfma16(X, bg0[n_], acc[M][n_]);                            \
      acc[M][n_] = mfma16(Y, bg1[n_], acc[M][n_]);                            \
    }                                                                         \
  } while (0)

#define DTILE_FF(SB, DOSTAGE) do {                                            \
    bf16x8 bg0[4], bg1[4], e0, e1, o0, o1;                                    \
    _Pragma("unroll")                                                         \
    for (int n_ = 0; n_ < 4; ++n_) {                                          \
      bg0[n_] = *(const bf16x8*)&(SB)[b0 + n_ * 1024];                        \
      bg1[n_] = *(const bf16x8*)&(SB)[b1 + n_ * 1024];                        \
    }                                                                         \
    e0 = *(const bf16x8*)&(SB)[a0];                                           \
    e1 = *(const bf16x8*)&(SB)[a1];                                           \
    o0 = *(const bf16x8*)&(SB)[a0 + 1024];                                    \
    o1 = *(const bf16x8*)&(SB)[a1 + 1024];                                    \
    if (DOSTAGE) DSTAGE6;                                                     \
    MFMA_D(e0, e1, 0);                                                        \
    e0 = *(const bf16x8*)&(SB)[a0 + 2048];                                    \
    e1 = *(const bf16x8*)&(SB)[a1 + 2048];                                    \
    MFMA_D(o0, o1, 1);                                                        \
    o0 = *(const bf16x8*)&(SB)[a0 + 3072];                                    \
    o1 = *(const bf16x8*)&(SB)[a1 + 3072];                                    \
    MFMA_D(e0, e1, 2);                                                        \
    MFMA_D(o0, o1, 3);                                                        \
    asm volatile("s_waitcnt lgkmcnt(0)" ::: "memory");                        \
    asm volatile("s_waitcnt vmcnt(0)" ::: "memory");                          \
    asm volatile("s_barrier" ::: "memory");                                   \
  } while (0)

// grid: 256 blocks (16 x 16), XCD-swizzled.
__global__ __launch_bounds__(512, 1) void dense_gemm(
    const unsigned short* __restrict__ A,
    const unsigned short* __restrict__ B,
    const float* __restrict__ bias,
    float* __restrict__ out)
{
  __shared__ unsigned short smd[2 * DBUFS];   // 96 KB
  int id  = blockIdx.x;
  int swz = (id & 7) * (gridDim.x >> 3) + (id >> 3);
  const int m0 = (swz / 16) * 256, n0 = (swz % 16) * 128;
  const int t = threadIdx.x, l = t & 63, w = t >> 6;
  const int wm = w >> 1, wn = w & 1;
  const int fr = l & 15, fg = l >> 4;
  const int fx = fr & 7;
  const int srow = l >> 3;
  const int sgr  = ((l & 7) ^ srow) * 8;
  const unsigned short* Aw = A + (size_t)(m0 + w * 32 + srow) * KDIM + sgr;
  const unsigned short* Bw = B + (size_t)(n0 + w * 16 + srow) * KDIM + sgr;
  const int a0 = (wm * 64 + fr) * 64 + ((fg ^ fx) * 8);
  const int a1 = (wm * 64 + fr) * 64 + (((4 + fg) ^ fx) * 8);
  const int b0 = 16384 + (wn * 64 + fr) * 64 + ((fg ^ fx) * 8);
  const int b1 = 16384 + (wn * 64 + fr) * 64 + (((4 + fg) ^ fx) * 8);
  f32x4 acc[4][4] = {};

  { // prologue
    unsigned short* db = smd;
    size_t koff = 0;
    DSTAGE6;
  }
  asm volatile("s_waitcnt vmcnt(0)" ::: "memory");
  asm volatile("s_barrier" ::: "memory");

#pragma unroll 1
  for (int kt = 0; kt < NT64; ++kt) {
    const unsigned short* sb = &smd[(kt & 1) * DBUFS];
    unsigned short* db = &smd[((kt + 1) & 1) * DBUFS];
    size_t koff = (size_t)(kt + 1) * BK64;
    DTILE_FF(sb, (kt < NT64 - 1));
  }

  const int g4 = fg * 4;
#pragma unroll
  for (int n = 0; n < 4; ++n) {
    int ncol = n0 + wn * 64 + n * 16 + fr;
    float bv = bias[ncol];
#pragma unroll
    for (int m = 0; m < 4; ++m) {
#pragma unroll
      for (int j = 0; j < 4; ++j) {
        int r = m0 + wm * 64 + m * 16 + g4 + j;
        out[(size_t)r * HID + ncol] = acc[m][n][j] + bv;
      }
    }
  }
}

// ---------------- causal flash attention, paired q-tiles ----------------
// grid (16 pairs, 32 bh); block 256 = 4 waves x 16 q-rows per tile.
// Block handles q-tiles {pair, 31-pair}: exactly 33 tile-computes each.
__global__ __launch_bounds__(256, 2) void attn_fwd(
    const unsigned short* __restrict__ Q,
    const unsigned short* __restrict__ K,
    const unsigned short* __restrict__ Vt,   // [bh][d][s]
    unsigned short* __restrict__ ctx)
{
  __shared__ unsigned short Ksh[2][64 * 128];   // swizzled granules, 16KB each
  __shared__ unsigned short Vsh[2][128 * 64];   // [d][key] swizzled, 16KB each
  __shared__ unsigned short Psh[4][16 * 72];    // per-wave P tile
  const int t = threadIdx.x, l = t & 63, w = t >> 6;
  int nwg = gridDim.x * gridDim.y;              // 512
  int id  = blockIdx.y * gridDim.x + blockIdx.x;
  int swz = (id & 7) * (nwg >> 3) + (id >> 3);
  const int pair = swz & 15;
  const int bh   = swz >> 4;
  const int qtA = pair, qtB = 31 - pair;
  const int fr = l & 15, fg = l >> 4;
  const size_t base  = (size_t)bh * SEQ * HD;
  const size_t vbase = (size_t)bh * HD * SEQ;

#define STAGE(BUF, KT) do {                                                   \
    const unsigned short* Kt_ = K + base + (size_t)((KT) * 64) * HD;          \
    _Pragma("unroll")                                                         \
    for (int i_ = 0; i_ < 4; ++i_) {                                          \
      int ch_  = w * 4 + i_;                                                  \
      int row_ = ch_ * 4 + (l >> 4);                                          \
      int c16_ = (l & 15) ^ (row_ & 7);                                       \
      gl_lds16(Kt_ + (size_t)row_ * HD + c16_ * 8, &Ksh[BUF][ch_ * 512]);     \
    }                                                                         \
    const unsigned short* Vg_ = Vt + vbase + (KT) * 64;                       \
    _Pragma("unroll")                                                         \
    for (int i_ = 0; i_ < 4; ++i_) {                                          \
      int ch_  = w * 4 + i_;                                                  \
      int row_ = ch_ * 8 + (l >> 3);                                          \
      int c16_ = (l & 7) ^ (row_ & 7);                                        \
      gl_lds16(Vg_ + (size_t)row_ * SEQ + c16_ * 8, &Vsh[BUF][ch_ * 512]);    \
    }                                                                         \
  } while (0)

#define COMPUTE_TILE(QF, OACC, MROW, LROW, QT) do {                           \
    f32x4 sacc[4] = {};                                                       \
    _Pragma("unroll")                                                         \
    for (int c_ = 0; c_ < 4; ++c_) {                                          \
      _Pragma("unroll")                                                       \
      for (int n_ = 0; n_ < 4; ++n_) {                                        \
        int krow = n_ * 16 + fr;                                              \
        int g_   = (c_ * 4 + fg) ^ (krow & 7);                                \
        bf16x8 kf = *(const bf16x8*)&Ksh[buf][krow * 128 + g_ * 8];           \
        sacc[n_] = mfma16(QF[c_], kf, sacc[n_]);                              \
      }                                                                       \
    }                                                                         \
    if (kt == (QT)) {                                                         \
      _Pragma("unroll")                                                       \
      for (int n_ = 0; n_ < 4; ++n_)                                          \
        _Pragma("unroll")                                                     \
        for (int j_ = 0; j_ < 4; ++j_)                                        \
          if (n_ * 16 + fr > w * 16 + fg * 4 + j_) sacc[n_][j_] = -1e30f;     \
    }                                                                         \
    float tm_[4];                                                             \
    _Pragma("unroll")                                                         \
    for (int j_ = 0; j_ < 4; ++j_) {                                          \
      float v0 = fmaxf(fmaxf(sacc[0][j_], sacc[1][j_]),                       \
                       fmaxf(sacc[2][j_], sacc[3][j_]));                      \
      v0 = fmaxf(v0, __shfl_xor(v0, 1));                                      \
      v0 = fmaxf(v0, __shfl_xor(v0, 2));                                      \
      v0 = fmaxf(v0, __shfl_xor(v0, 4));                                      \
      v0 = fmaxf(v0, __shfl_xor(v0, 8));                                      \
      tm_[j_] = v0;                                                           \
    }                                                                         \
    float sc_[4], ps_[4];                                                     \
    _Pragma("unroll")                                                         \
    for (int j_ = 0; j_ < 4; ++j_) {                                          \
      float mn_ = fmaxf(MROW[j_], tm_[j_]);                                   \
      sc_[j_] = exp2f((MROW[j_] - mn_) * LOG2E);                              \
      MROW[j_] = mn_;                                                         \
      ps_[j_] = 0.f;                                                          \
    }                                                                         \
    _Pragma("unroll")                                                         \
    for (int n_ = 0; n_ < 4; ++n_)                                            \
      _Pragma("unroll")                                                       \
      for (int j_ = 0; j_ < 4; ++j_) {                                        \
        float p_ = exp2f((sacc[n_][j_] - MROW[j_]) * LOG2E);                  \
        sacc[n_][j_] = p_;                                                    \
        ps_[j_] += p_;                                                        \
      }                                                                       \
    _Pragma("unroll")                                                         \
    for (int j_ = 0; j_ < 4; ++j_) {                                          \
      float s_ = ps_[j_];                                                     \
      s_ += __shfl_xor(s_, 1);                                                \
      s_ += __shfl_xor(s_, 2);                                                \
      s_ += __shfl_xor(s_, 4);                                                \
      s_ += __shfl_xor(s_, 8);                                                \
      LROW[j_] = LROW[j_] * sc_[j_] + s_;                                     \
    }                                                                         \
    _Pragma("unroll")                                                         \
    for (int n_ = 0; n_ < 8; ++n_)                                            \
      _Pragma("unroll")                                                       \
      for (int j_ = 0; j_ < 4; ++j_)                                          \
        OACC[n_][j_] *= sc_[j_];                                              \
    _Pragma("unroll")                                                         \
    for (int n_ = 0; n_ < 4; ++n_)                                            \
      _Pragma("unroll")                                                       \
      for (int j_ = 0; j_ < 4; ++j_)                                          \
        Psh[w][(fg * 4 + j_) * 72 + n_ * 16 + fr] = f2bf(sacc[n_][j_]);       \
    _Pragma("unroll")                                                         \
    for (int ks_ = 0; ks_ < 2; ++ks_) {                                       \
      bf16x8 pf = *(const bf16x8*)&Psh[w][fr * 72 + ks_ * 32 + fg * 8];       \
      _Pragma("unroll")                                                       \
      for (int n_ = 0; n_ < 8; ++n_) {                                        \
        int vrow = n_ * 16 + fr;                                              \
        int g_   = (ks_ * 4 + fg) ^ (vrow & 7);                               \
        bf16x8 vf = *(const bf16x8*)&Vsh[buf][vrow * 64 + g_ * 8];            \
        OACC[n_] = mfma16(pf, vf, OACC[n_]);                                  \
      }                                                                       \
    }                                                                         \
  } while (0)

  // Q fragments for both tiles (scale folded in at QKV epilogue)
  bf16x8 qfA[4], qfB[4];
  {
    const unsigned short* qpA = Q + base + (size_t)(qtA * 64 + w * 16 + fr) * HD + fg * 8;
    const unsigned short* qpB = Q + base + (size_t)(qtB * 64 + w * 16 + fr) * HD + fg * 8;
#pragma unroll
    for (int c = 0; c < 4; ++c) {
      qfA[c] = *(const bf16x8*)(qpA + c * 32);
      qfB[c] = *(const bf16x8*)(qpB + c * 32);
    }
  }
  f32x4 oaccA[8] = {}, oaccB[8] = {};
  float mA[4] = {-1e30f, -1e30f, -1e30f, -1e30f};
  float mB[4] = {-1e30f, -1e30f, -1e30f, -1e30f};
  float lA[4] = {0.f, 0.f, 0.f, 0.f};
  float lB[4] = {0.f, 0.f, 0.f, 0.f};

  STAGE(0, 0);
  __syncthreads();
  int buf = 0;
  for (int kt = 0; kt <= qtB; ++kt) {
    if (kt < qtB) STAGE(buf ^ 1, kt + 1);       // prefetch hides under compute
    COMPUTE_TILE(qfB, oaccB, mB, lB, qtB);
    if (kt <= qtA) COMPUTE_TILE(qfA, oaccA, mA, lA, qtA);
    __syncthreads();                            // drains vmcnt -> next buf ready
    buf ^= 1;
  }

  const int bb = bh >> 4, h = bh & 15;
#define WRITE_CTX(OACC, LROW, QT) do {                                        \
    _Pragma("unroll")                                                         \
    for (int n_ = 0; n_ < 8; ++n_)                                            \
      _Pragma("unroll")                                                       \
      for (int j_ = 0; j_ < 4; ++j_) {                                        \
        int qrow = (QT) * 64 + w * 16 + fg * 4 + j_;                          \
        float val = OACC[n_][j_] / LROW[j_];                                  \
        ctx[((size_t)(qrow * BATCH + bb)) * HID + h * HD + n_ * 16 + fr] =    \
            f2bf(val);                                                        \
      }                                                                       \
  } while (0)
  WRITE_CTX(oaccA, lA, qtA);
  WRITE_CTX(oaccB, lB, qtB);
#undef STAGE
#undef COMPUTE_TILE
#undef WRITE_CTX
}

// ---------------- launcher ----------------
extern "C" void kernel_launch(void* const* d_in, const int* in_sizes, int n_in,
                              void* d_out, int out_size, void* d_ws, size_t ws_size,
                              hipStream_t stream) {
  const float* hs      = (const float*)d_in[0];
  const float* w_qkv   = (const float*)d_in[1];
  const float* b_qkv   = (const float*)d_in[2];
  const float* w_dense = (const float*)d_in[3];
  const float* b_dense = (const float*)d_in[4];
  float* out = (float*)d_out;

  unsigned short* hsb = (unsigned short*)d_ws;              // 8.4M shorts
  unsigned short* wqb = hsb + (size_t)MTOT * HID;
  unsigned short* wdb = wqb + (size_t)NQKV * HID;
  unsigned short* q   = wdb + (size_t)HID * HID;
  unsigned short* k   = q   + (size_t)MTOT * HID;
  unsigned short* vt  = k   + (size_t)MTOT * HID;           // V transposed [bh][d][s]
  unsigned short* ctx = vt  + (size_t)MTOT * HID;

  cvt3_f32_bf16<<<2048, 256, 0, stream>>>(
      hs, hsb, (MTOT * HID) / 4,
      w_qkv, wqb, (NQKV * HID) / 4,
      w_dense, wdb, (HID * HID) / 4);

  qkv_gemm<<<dim3((MTOT / 256) * (NQKV / 256)), 512, 0, stream>>>(hsb, wqb, b_qkv, q, k, vt);
  attn_fwd<<<dim3(16, 32), 256, 0, stream>>>(q, k, vt, ctx);
  dense_gemm<<<dim3((MTOT / 256) * (HID / 128)), 512, 0, stream>>>(ctx, wdb, b_dense, out);
}